// Round 1
// baseline (2741.562 us; speedup 1.0000x reference)
//
#include <hip/hip_runtime.h>
#include <hip/hip_fp16.h>

// GRU: T=2048, B=64, I=H=256.  out = ([T,B,H] f32, initial hx)
//
// Design:
//  1) cvt_init: f32->f16 weight copies into ws, h_state := hx, write hx tail of d_out.
//  2) gi_gemm:  gi[t*B+b, n] = sum_k x[t,b,k]*x2h_w[n,k] + x2h_b[n], f16 MFMA 16x16x32,
//               fragments loaded straight from global (W is L2-resident), gi stored f16 in ws.
//  3) gru_rec:  64 WGs (one per batch element) x 768 threads. Thread j holds h2h_w row j
//               as 128 packed-f16 VGPRs for the whole sequence. Per step:
//               dot(h) via v_dot2_f32_f16 with h broadcast from LDS, gates on threads j<256.
//               Only __syncthreads() between steps — h never leaves the CU.
//  T is chunked adaptively so the f16 gi buffer fits ws_size.

typedef _Float16 half2v __attribute__((ext_vector_type(2)));
typedef _Float16 half8  __attribute__((ext_vector_type(8)));
typedef float    f32x4  __attribute__((ext_vector_type(4)));

#define T_SEQ 2048
#define BATCH 64
#define HDIM  256
#define G3    768   // 3*H

__device__ __forceinline__ half2v u2h(unsigned int u) {
    union { unsigned int u; half2v h; } c; c.u = u; return c.h;
}

__device__ __forceinline__ float fdot2(half2v a, half2v b, float c) {
#if __has_builtin(__builtin_amdgcn_fdot2)
    return __builtin_amdgcn_fdot2(a, b, c, false);
#else
    return c + (float)a[0] * (float)b[0] + (float)a[1] * (float)b[1];
#endif
}

// ---------------------------------------------------------------- cvt_init
__global__ void cvt_init(const float* __restrict__ x2h_w, const float* __restrict__ h2h_w,
                         const float* __restrict__ hx,
                         _Float16* __restrict__ wx16, _Float16* __restrict__ wh16,
                         float* __restrict__ hstate, float* __restrict__ out_tail) {
    int i = blockIdx.x * 256 + threadIdx.x;
    if (i < G3 * HDIM) {
        wx16[i] = (_Float16)x2h_w[i];
        wh16[i] = (_Float16)h2h_w[i];
    }
    if (i < BATCH * HDIM) {
        float v = hx[i];
        hstate[i] = v;
        out_tail[i] = v;   // second output = INITIAL hx
    }
}

// ---------------------------------------------------------------- gi_gemm
// Grid: (nrows/256) WGs of 256 threads (4 waves). Wave handles 64 rows (4 strips of 16).
// mfma_f32_16x16x32_f16 layouts (m89-verified family):
//   A: lane holds A[row=l&15, k=(l>>4)*8+i]   B: lane holds B[k=(l>>4)*8+i, col=l&15]
//   D: lane holds C[row=(l>>4)*4+r, col=l&15]
__global__ __launch_bounds__(256) void gi_gemm(const float* __restrict__ x,
                                               const _Float16* __restrict__ wx,
                                               const float* __restrict__ bx,
                                               _Float16* __restrict__ gi,
                                               int row_base) {
    const int lane  = threadIdx.x & 63;
    const int wave  = threadIdx.x >> 6;
    const int l15   = lane & 15;
    const int kslot = lane >> 4;               // 0..3
    const int row0  = row_base + blockIdx.x * 256 + wave * 64;

    half8 a[4][8];
    #pragma unroll
    for (int s = 0; s < 4; ++s) {
        const float* xr = x + (size_t)(row0 + s * 16 + l15) * HDIM + kslot * 8;
        #pragma unroll
        for (int kt = 0; kt < 8; ++kt) {
            float4 lo = *(const float4*)(xr + kt * 32);
            float4 hi = *(const float4*)(xr + kt * 32 + 4);
            half8 v;
            v[0] = (_Float16)lo.x; v[1] = (_Float16)lo.y; v[2] = (_Float16)lo.z; v[3] = (_Float16)lo.w;
            v[4] = (_Float16)hi.x; v[5] = (_Float16)hi.y; v[6] = (_Float16)hi.z; v[7] = (_Float16)hi.w;
            a[s][kt] = v;
        }
    }

    for (int nt = 0; nt < 48; ++nt) {
        half8 b[8];
        const _Float16* wr = wx + (size_t)(nt * 16 + l15) * HDIM + kslot * 8;
        #pragma unroll
        for (int kt = 0; kt < 8; ++kt) b[kt] = *(const half8*)(wr + kt * 32);
        const int   col  = nt * 16 + l15;
        const float bias = bx[col];
        #pragma unroll
        for (int s = 0; s < 4; ++s) {
            f32x4 acc = {0.f, 0.f, 0.f, 0.f};
            #pragma unroll
            for (int kt = 0; kt < 8; ++kt)
                acc = __builtin_amdgcn_mfma_f32_16x16x32_f16(a[s][kt], b[kt], acc, 0, 0, 0);
            #pragma unroll
            for (int r = 0; r < 4; ++r) {
                int rowl = (row0 - row_base) + s * 16 + kslot * 4 + r;
                gi[(size_t)rowl * G3 + col] = (_Float16)(acc[r] + bias);
            }
        }
    }
}

// ---------------------------------------------------------------- gru_rec
// 64 WGs x 768 threads. Thread j owns h2h_w row j (128 VGPRs of packed f16).
__global__ __launch_bounds__(768, 3) void gru_rec(const _Float16* __restrict__ gi,
                                                  const _Float16* __restrict__ wh,
                                                  const float* __restrict__ bh,
                                                  const float* __restrict__ hx,
                                                  float* __restrict__ hstate,
                                                  float* __restrict__ out,
                                                  int t_start, int t_len) {
    __shared__ __align__(16) _Float16 lds_h[HDIM];
    __shared__ float ghbuf[G3];
    __shared__ float ginbuf[HDIM];

    const int j = threadIdx.x;
    const int b = blockIdx.x;

    // weight row j -> registers (fully unrolled => static VGPR indices)
    uint4 w[32];
    const uint4* wrow = (const uint4*)(wh + (size_t)j * HDIM);
    #pragma unroll
    for (int i = 0; i < 32; ++i) w[i] = wrow[i];
    const float bias = bh[j];

    float h_old = 0.f;
    if (j < HDIM) {
        h_old = (t_start == 0) ? hx[b * HDIM + j] : hstate[b * HDIM + j];
        lds_h[j] = (_Float16)h_old;
    }
    __syncthreads();

    const _Float16* gip = gi + (size_t)b * G3 + j;
    float gi_next = (float)gip[0];

    for (int tt = 0; tt < t_len; ++tt) {
        const float gi_cur = gi_next;
        const int nxt = (tt + 1 < t_len) ? tt + 1 : tt;
        gi_next = (float)gip[(size_t)nxt * BATCH * G3];   // prefetch next step

        // gh[j] = dot(W_h[j,:], h) ; h broadcast from LDS (conflict-free)
        float acc = 0.f;
        const uint4* hp = (const uint4*)lds_h;
        #pragma unroll
        for (int i = 0; i < 32; ++i) {
            uint4 hv = hp[i];
            uint4 wv = w[i];
            acc = fdot2(u2h(wv.x), u2h(hv.x), acc);
            acc = fdot2(u2h(wv.y), u2h(hv.y), acc);
            acc = fdot2(u2h(wv.z), u2h(hv.z), acc);
            acc = fdot2(u2h(wv.w), u2h(hv.w), acc);
        }
        float gh = acc + bias;
        if (j < 512) {
            ghbuf[j] = gh + gi_cur;        // r,z: i_g + h_g combined
        } else {
            ghbuf[j] = gh;                 // n: keep h_n separate (scaled by r)
            ginbuf[j - 512] = gi_cur;
        }
        __syncthreads();

        if (j < HDIM) {
            float sr = ghbuf[j], sz = ghbuf[j + 256], hn = ghbuf[j + 512];
            float r = 1.f / (1.f + __expf(-sr));
            float z = 1.f / (1.f + __expf(-sz));
            float n = tanhf(ginbuf[j] + r * hn);
            float hnew = (1.f - z) * n + z * h_old;
            out[((size_t)(t_start + tt) * BATCH + b) * HDIM + j] = hnew;
            h_old = hnew;
            lds_h[j] = (_Float16)hnew;
        }
        __syncthreads();
    }
    if (j < HDIM) hstate[b * HDIM + j] = h_old;
}

// ---------------------------------------------------------------- host
extern "C" void kernel_launch(void* const* d_in, const int* in_sizes, int n_in,
                              void* d_out, int out_size, void* d_ws, size_t ws_size,
                              hipStream_t stream) {
    const float* x     = (const float*)d_in[0];
    const float* hx    = (const float*)d_in[1];
    const float* x2h_w = (const float*)d_in[2];
    const float* h2h_w = (const float*)d_in[3];
    const float* x2h_b = (const float*)d_in[4];
    const float* h2h_b = (const float*)d_in[5];
    float* out = (float*)d_out;

    char* ws = (char*)d_ws;
    _Float16* wx16   = (_Float16*)ws;                    // 393216 B
    _Float16* wh16   = (_Float16*)(ws + 393216);         // 393216 B
    float*    hstate = (float*)(ws + 786432);            // 65536 B
    _Float16* gi     = (_Float16*)(ws + 851968);

    size_t gi_cap_elems = (ws_size > 851968) ? (ws_size - 851968) / 2 : 0;
    int CT = T_SEQ;
    while ((size_t)CT * BATCH * G3 > gi_cap_elems && CT > 64) CT >>= 1;

    cvt_init<<<768, 256, 0, stream>>>(x2h_w, h2h_w, hx, wx16, wh16, hstate,
                                      out + (size_t)T_SEQ * BATCH * HDIM);

    for (int t0 = 0; t0 < T_SEQ; t0 += CT) {
        int rows = CT * BATCH;
        gi_gemm<<<rows / 256, 256, 0, stream>>>(x, wx16, x2h_b, gi, t0 * BATCH);
        gru_rec<<<BATCH, 768, 0, stream>>>(gi, wh16, h2h_b, hx, hstate, out, t0, CT);
    }
}